// Round 2
// baseline (475.421 us; speedup 1.0000x reference)
//
#include <hip/hip_runtime.h>
#include <stdint.h>

// ---------------------------------------------------------------------------
// QuantLinear via EXACT int8 path:
//   qx[t,k] int8, sx[t,g] (g=k/128) ; qw[o,k] int8, sw[o]
//   out[t,o] = sw[o] * sum_g sx[t,g] * (int dot over group g) + bias[o]
// R5: GEMM rebuilt as 256x256 8-phase counted-vmcnt pipeline (T1+T2+T3+T4+T5):
//   BK=128 (= one quant group), 512 thr / 8 waves (2Mx4N), LDS 128KB dbuf,
//   chunk-XOR swizzle kept (bank-conflict 0), raw s_barrier + derived
//   vmcnt(4)/vmcnt(2) waits (never 0 in loop), setprio around MFMA clusters,
//   bijective XCD block swizzle. Quant kernels unchanged from R4.
// ---------------------------------------------------------------------------

typedef __attribute__((ext_vector_type(4))) int   i32x4;
typedef __attribute__((ext_vector_type(4))) float f32x4;

static __device__ __forceinline__ void load_lds16(const void* g, void* l) {
    __builtin_amdgcn_global_load_lds(
        (const __attribute__((address_space(1))) void*)g,
        (__attribute__((address_space(3))) void*)l, 16, 0, 0);
}

static __device__ __forceinline__ int8_t q8m(float v, float inv) {
    float q = rintf(v * inv);                   // half-even, matches np
    q = fminf(fmaxf(q, -128.0f), 127.0f);
    return (int8_t)(int)q;
}

// ---------------- act quant: one row per block -----------------------------
// thread t owns floats [16t, 16t+16); group of 128 = 8 consecutive threads.
// K hard-assumed 4096 (256 threads x 16 floats), group_size = 128.
__global__ __launch_bounds__(256) void quant_act_kernel(
        const float* __restrict__ x, int8_t* __restrict__ xq,
        float* __restrict__ sxT, int M) {
    const int row = blockIdx.x, t = threadIdx.x;
    const float* xr = x + (size_t)row * 4096;
    float4 v[4];
#pragma unroll
    for (int i = 0; i < 4; i++)
        v[i] = *(const float4*)(xr + t * 16 + i * 4);
    float m = 0.0f;
#pragma unroll
    for (int i = 0; i < 4; i++)
        m = fmaxf(m, fmaxf(fmaxf(fabsf(v[i].x), fabsf(v[i].y)),
                           fmaxf(fabsf(v[i].z), fabsf(v[i].w))));
    m = fmaxf(m, __shfl_xor(m, 1));
    m = fmaxf(m, __shfl_xor(m, 2));
    m = fmaxf(m, __shfl_xor(m, 4));
    const float scale = fmaxf(m / 127.0f, 1e-8f);
    const float inv = 1.0f / scale;
    union { int8_t b[16]; i32x4 w; } o;
#pragma unroll
    for (int i = 0; i < 4; i++) {
        o.b[i * 4 + 0] = q8m(v[i].x, inv);
        o.b[i * 4 + 1] = q8m(v[i].y, inv);
        o.b[i * 4 + 2] = q8m(v[i].z, inv);
        o.b[i * 4 + 3] = q8m(v[i].w, inv);
    }
    *(i32x4*)(xq + (size_t)row * 4096 + t * 16) = o.w;
    if ((t & 7) == 0)                       // sxT layout [G, M]
        sxT[(size_t)(t >> 3) * M + row] = scale;
}

// ---------------- weight quant: one row per block, per-row scale -----------
__global__ __launch_bounds__(256) void quant_wgt_kernel(
        const float* __restrict__ w, int8_t* __restrict__ wq,
        float* __restrict__ sw) {
    const int row = blockIdx.x, t = threadIdx.x;
    const float* wr = w + (size_t)row * 4096;
    float4 v[4];
#pragma unroll
    for (int i = 0; i < 4; i++)
        v[i] = *(const float4*)(wr + t * 16 + i * 4);
    float m = 0.0f;
#pragma unroll
    for (int i = 0; i < 4; i++)
        m = fmaxf(m, fmaxf(fmaxf(fabsf(v[i].x), fabsf(v[i].y)),
                           fmaxf(fabsf(v[i].z), fabsf(v[i].w))));
#pragma unroll
    for (int off = 1; off < 64; off <<= 1)
        m = fmaxf(m, __shfl_xor(m, off));
    __shared__ float wm[4];
    if ((t & 63) == 0) wm[t >> 6] = m;
    __syncthreads();
    m = fmaxf(fmaxf(wm[0], wm[1]), fmaxf(wm[2], wm[3]));
    const float scale = fmaxf(m / 127.0f, 1e-8f);
    if (t == 0) sw[row] = scale;
    const float inv = 1.0f / scale;
    union { int8_t b[16]; i32x4 w4; } o;
#pragma unroll
    for (int i = 0; i < 4; i++) {
        o.b[i * 4 + 0] = q8m(v[i].x, inv);
        o.b[i * 4 + 1] = q8m(v[i].y, inv);
        o.b[i * 4 + 2] = q8m(v[i].z, inv);
        o.b[i * 4 + 3] = q8m(v[i].w, inv);
    }
    *(i32x4*)(wq + (size_t)row * 4096 + t * 16) = o.w4;
}

// ---------------- int8 GEMM: 256x256 tile, 8-phase counted-vmcnt -----------
// LDS image (A and B): row r (256 rows, 128 B each), 16B chunk c stored at
// byte r*128 + (c ^ (r&7))*16 — produced by permuting which global chunk each
// staging lane fetches (DMA dest fixed at wave-uniform base + lane*16).
// Per K-tile (=128 = one quant group): 4 phases, each = {ds_reads | 2 staging
// issues | barrier | lgkm0 | setprio(1) 16xMFMA + fold setprio(0) | barrier}.
// Staging order for tile j+1 during tile j: B0,B64 | B128,B192 | A0,A128 |
// A64,A192.  Derived waits: vmcnt(4) end of ph2 (retires A64/A192 of tile j,
// read by ph3), vmcnt(2) end of ph4 (retires B*+A0/A128 of tile j+1, read by
// next ph1; leaves A64/A192 of tile j+1 in flight). Never drains to 0.
#define QUAD(mh, nh)                                                         \
    _Pragma("unroll")                                                        \
    for (int mi2 = 0; mi2 < 4; ++mi2) {                                      \
        _Pragma("unroll")                                                    \
        for (int nj = 0; nj < 2; ++nj) {                                     \
            const int ni = (nh) * 2 + nj;                                    \
            i32x4 t = __builtin_amdgcn_mfma_i32_16x16x64_i8(                 \
                a[mi2][0], b[ni][0], (i32x4){0, 0, 0, 0}, 0, 0, 0);          \
            t = __builtin_amdgcn_mfma_i32_16x16x64_i8(                       \
                a[mi2][1], b[ni][1], t, 0, 0, 0);                            \
            _Pragma("unroll")                                                \
            for (int r = 0; r < 4; ++r)                                      \
                acc[(mh) * 4 + mi2][ni][r] += (float)t[r] * sxv[mi2][r];     \
        }                                                                    \
    }

__global__ __launch_bounds__(512, 2) void gemm_i8_kernel(
        const int8_t* __restrict__ A, const int8_t* __restrict__ B,
        const float* __restrict__ sxT, const float* __restrict__ sw,
        const float* __restrict__ bias, float* __restrict__ C,
        int M, int N, int K) {
    __shared__ __align__(16) int8_t As[2][256 * 128];   // 64 KB
    __shared__ __align__(16) int8_t Bs[2][256 * 128];   // 64 KB
    const int tid = threadIdx.x;
    const int wave = tid >> 6, lane = tid & 63;

    // bijective XCD swizzle (nwg multiple of 8)
    const int nwg = gridDim.x, nN = N >> 8;
    const int wg = ((int)blockIdx.x & 7) * (nwg >> 3) + ((int)blockIdx.x >> 3);
    const int bm = (wg / nN) << 8, bn = (wg % nN) << 8;

    const int wm = (wave >> 2) << 7, wn = (wave & 3) << 6;   // 128x64 / wave
    const int fr = lane & 15, q = lane >> 4, r7 = lane & 7;

    // staging: call(rbase) covers rows rbase + wave*8 + (lane>>3);
    // lane fetches global chunk (lane&7)^((lane>>3)&7) -> XOR-swizzled LDS.
    const int srow = wave * 8 + (lane >> 3);
    const int scol = ((lane & 7) ^ ((lane >> 3) & 7)) << 4;
    const size_t sK = (size_t)K;
    const int8_t* Ag = A + (size_t)(bm + srow) * sK + scol;
    const int8_t* Bg = B + (size_t)(bn + srow) * sK + scol;
    const int sldsw = wave * 8 * 128;   // wave-uniform LDS base within a call

    f32x4 acc[8][4];
#pragma unroll
    for (int i = 0; i < 8; i++)
#pragma unroll
        for (int jn = 0; jn < 4; jn++) acc[i][jn] = (f32x4){0.f, 0.f, 0.f, 0.f};

    // fragment read bases: row = (wm|wn) + mi*16 + fr; chunk (h*4+q)^r7
    const int abase = (wm + fr) * 128;
    const int bbase = (wn + fr) * 128;
    const int c0 = (q ^ r7) << 4, c1 = ((4 + q) ^ r7) << 4;
    const float* sxw = sxT + bm + wm + q * 4;   // + j*M (+64 for mh1) per tile

    const int NT = K >> 7;

    // prologue: stage tile 0 -> buf 0, same order as steady state
    load_lds16(Bg,             &Bs[0][sldsw]);
    load_lds16(Bg +  64 * sK,  &Bs[0][ 64 * 128 + sldsw]);
    load_lds16(Bg + 128 * sK,  &Bs[0][128 * 128 + sldsw]);
    load_lds16(Bg + 192 * sK,  &Bs[0][192 * 128 + sldsw]);
    load_lds16(Ag,             &As[0][sldsw]);
    load_lds16(Ag + 128 * sK,  &As[0][128 * 128 + sldsw]);
    load_lds16(Ag +  64 * sK,  &As[0][ 64 * 128 + sldsw]);
    load_lds16(Ag + 192 * sK,  &As[0][192 * 128 + sldsw]);
    asm volatile("s_waitcnt vmcnt(2)" ::: "memory");   // A64,A192 may fly
    __builtin_amdgcn_s_barrier();

    for (int j = 0; j < NT; ++j) {
        const int cur = j & 1, nxt = cur ^ 1;
        const size_t kn = (size_t)((j + 1 < NT) ? j + 1 : j) << 7;
        const int8_t* Ac = As[cur];
        const int8_t* Bc = Bs[cur];
        const float* sxg = sxw + (size_t)j * M;

        i32x4 a[4][2], b[4][2];
        f32x4 sxv[4];

        // ---- phase 1: quad(0,0); reads a(mh0)+b(all); stage B0,B64 ----
#pragma unroll
        for (int i = 0; i < 4; ++i) {
            a[i][0] = *(const i32x4*)(Ac + abase + i * 2048 + c0);
            a[i][1] = *(const i32x4*)(Ac + abase + i * 2048 + c1);
            b[i][0] = *(const i32x4*)(Bc + bbase + i * 2048 + c0);
            b[i][1] = *(const i32x4*)(Bc + bbase + i * 2048 + c1);
        }
#pragma unroll
        for (int i = 0; i < 4; ++i)
            sxv[i] = *(const f32x4*)(sxg + i * 16);
        load_lds16(Bg + kn,            &Bs[nxt][sldsw]);
        load_lds16(Bg + kn + 64 * sK,  &Bs[nxt][64 * 128 + sldsw]);
        __builtin_amdgcn_s_barrier();
        asm volatile("s_waitcnt lgkmcnt(0)" ::: "memory");
        __builtin_amdgcn_sched_barrier(0);
        __builtin_amdgcn_s_setprio(1);
        QUAD(0, 0)
        __builtin_amdgcn_s_setprio(0);
        __builtin_amdgcn_s_barrier();

        // ---- phase 2: quad(0,1); stage B128,B192 ----
        load_lds16(Bg + kn + 128 * sK, &Bs[nxt][128 * 128 + sldsw]);
        load_lds16(Bg + kn + 192 * sK, &Bs[nxt][192 * 128 + sldsw]);
        __builtin_amdgcn_s_barrier();
        __builtin_amdgcn_sched_barrier(0);
        __builtin_amdgcn_s_setprio(1);
        QUAD(0, 1)
        __builtin_amdgcn_s_setprio(0);
        asm volatile("s_waitcnt vmcnt(4)" ::: "memory");  // A64,A192(j) landed
        __builtin_amdgcn_s_barrier();

        // ---- phase 3: quad(1,0); reads a(mh1); stage A0,A128 ----
#pragma unroll
        for (int i = 0; i < 4; ++i) {
            a[i][0] = *(const i32x4*)(Ac + abase + 64 * 128 + i * 2048 + c0);
            a[i][1] = *(const i32x4*)(Ac + abase + 64 * 128 + i * 2048 + c1);
        }
#pragma unroll
        for (int i = 0; i < 4; ++i)
            sxv[i] = *(const f32x4*)(sxg + 64 + i * 16);
        load_lds16(Ag + kn,            &As[nxt][sldsw]);
        load_lds16(Ag + kn + 128 * sK, &As[nxt][128 * 128 + sldsw]);
        __builtin_amdgcn_s_barrier();
        asm volatile("s_waitcnt lgkmcnt(0)" ::: "memory");
        __builtin_amdgcn_sched_barrier(0);
        __builtin_amdgcn_s_setprio(1);
        QUAD(1, 0)
        __builtin_amdgcn_s_setprio(0);
        __builtin_amdgcn_s_barrier();

        // ---- phase 4: quad(1,1); stage A64,A192 ----
        load_lds16(Ag + kn + 64 * sK,  &As[nxt][64 * 128 + sldsw]);
        load_lds16(Ag + kn + 192 * sK, &As[nxt][192 * 128 + sldsw]);
        __builtin_amdgcn_s_barrier();
        __builtin_amdgcn_sched_barrier(0);
        __builtin_amdgcn_s_setprio(1);
        QUAD(1, 1)
        __builtin_amdgcn_s_setprio(0);
        asm volatile("s_waitcnt vmcnt(2)" ::: "memory");  // next ph1 data in
        __builtin_amdgcn_s_barrier();
    }
    asm volatile("s_waitcnt vmcnt(0)" ::: "memory");  // drain dup staging

    // epilogue: C/D layout col=lane&15, row=(lane>>4)*4+reg; fold sw + bias
    const int or0 = bm + wm + q * 4;
    const int oc0 = bn + wn + fr;
    float swv[4], bv[4];
#pragma unroll
    for (int ni = 0; ni < 4; ni++) {
        swv[ni] = sw[oc0 + ni * 16];
        bv[ni] = bias[oc0 + ni * 16];
    }
#pragma unroll
    for (int mi = 0; mi < 8; mi++)
#pragma unroll
        for (int ni = 0; ni < 4; ni++)
#pragma unroll
            for (int r = 0; r < 4; r++)
                C[(size_t)(or0 + mi * 16 + r) * N + (oc0 + ni * 16)] =
                    acc[mi][ni][r] * swv[ni] + bv[ni];
}

extern "C" void kernel_launch(void* const* d_in, const int* in_sizes, int n_in,
                              void* d_out, int out_size, void* d_ws, size_t ws_size,
                              hipStream_t stream) {
    const float* x    = (const float*)d_in[0];
    const float* w    = (const float*)d_in[1];
    const float* bias = (const float*)d_in[2];
    // d_in[3] = group_size (128) — hard-assumed (8 threads x 16 floats per group).

    const int out_f  = in_sizes[2];
    const int in_f   = in_sizes[1] / out_f;   // 4096 (quant kernels assume this)
    const int tokens = in_sizes[0] / in_f;
    const int G = in_f / 128;

    int8_t* xq  = (int8_t*)d_ws;                         // [M,K] int8
    int8_t* wq  = xq + (size_t)tokens * in_f;            // [N,K] int8
    float*  sxT = (float*)(wq + (size_t)out_f * in_f);   // [G,M] fp32
    float*  sw  = sxT + (size_t)G * tokens;              // [N]  fp32
    float*  out = (float*)d_out;

    quant_act_kernel<<<tokens, 256, 0, stream>>>(x, xq, sxT, tokens);
    quant_wgt_kernel<<<out_f, 256, 0, stream>>>(w, wq, sw);

    const int nwg = (tokens / 256) * (out_f / 256);      // 512, %8 == 0
    gemm_i8_kernel<<<nwg, 512, 0, stream>>>(xq, wq, sxT, sw, bias, out,
                                            tokens, out_f, in_f);
}